// Round 6
// baseline (1031.623 us; speedup 1.0000x reference)
//
#include <hip/hip_runtime.h>
#include <hip/hip_bf16.h>

#define BB 512
#define VV 6890
#define NJ 24
#define NBETA 10
#define NP 207          // (24-1)*9
#define N3 (VV*3)       // 20670
#define TBAT 8          // batch tile in k_fused
#define NCH 16          // v-chunks in k_jreg
#define CHV ((VV + NCH - 1) / NCH)   // 431

// d_out element offsets (fp32), concatenated in return order:
// verts (B,V,3), posed_joints (B,J,3), A (B,J,4,4), transforms (B,J,4,4), v_posed (B,V,3)
#define OFF_VERTS 0
#define OFF_PJ   (BB*VV*3)
#define OFF_A    (OFF_PJ + BB*NJ*3)
#define OFF_TF   (OFF_A + BB*NJ*16)
#define OFF_VP   (OFF_TF + BB*NJ*16)

// ws layout (fp32 elements)
#define WS_JP   0                        // NCH*24*33 partials of [JT[3]|JS[30]]
#define WS_PF   (WS_JP + NCH*NJ*33)      // B*207 pose_feature
#define WS_A    (WS_PF + BB*NP)          // B*24*16 fp32 A

// SMPL parents are a compile-time constant in the reference — hardcoded.
__constant__ int c_par[NJ] = {-1, 0, 0, 0, 1, 2, 3, 4, 5, 6, 7, 8,
                              9, 9, 9, 12, 13, 14, 16, 17, 18, 19, 20, 21};

// ------------------------------------------------- K1: partial JT/JS sums
__global__ __launch_bounds__(256) void k_jreg(const float* __restrict__ jr,
                                              const float* __restrict__ vt,
                                              const float* __restrict__ sd,
                                              float* __restrict__ ws_jp) {
    int j = blockIdx.x, ch = blockIdx.y;
    int t = threadIdx.x;
    int v0 = ch * CHV;
    int vend = (v0 + CHV < VV) ? (v0 + CHV) : VV;

    float acc[33];
#pragma unroll
    for (int i = 0; i < 33; i++) acc[i] = 0.f;

    for (int v = v0 + t; v < vend; v += 256) {
        float a = jr[(size_t)j * VV + v];
        acc[0] += a * vt[v * 3 + 0];
        acc[1] += a * vt[v * 3 + 1];
        acc[2] += a * vt[v * 3 + 2];
        const float2* sp = (const float2*)&sd[(size_t)v * 30];   // 8B-aligned
#pragma unroll
        for (int i = 0; i < 15; i++) {
            float2 s = sp[i];
            acc[3 + 2 * i] += a * s.x;
            acc[4 + 2 * i] += a * s.y;
        }
    }

    __shared__ float red[33][256];
#pragma unroll
    for (int i = 0; i < 33; i++) red[i][t] = acc[i];
    __syncthreads();
    for (int s = 128; s > 0; s >>= 1) {
        if (t < s) {
#pragma unroll
            for (int i = 0; i < 33; i++) red[i][t] += red[i][t + s];
        }
        __syncthreads();
    }
    if (t < 33) ws_jp[(size_t)(ch * NJ + j) * 33 + t] = red[t][0];
}

// ------------------------------- K2: Jloc, Rodrigues, chain, A/transforms/joints
__global__ __launch_bounds__(64) void k_chain(
        const float* __restrict__ betas,
        const float* __restrict__ pose,
        const float* __restrict__ ws_jp,
        float* __restrict__ ws_pf,
        float* __restrict__ ws_A,
        float* __restrict__ out) {
    int b = blockIdx.x;
    int t = threadIdx.x;
    __shared__ float Jl[NJ][3];
    __shared__ float tm[NJ][16];
    __shared__ float ch[NJ][16];
    float R[9];

    if (t < NJ) {
        int j = t;
        float s[33];
#pragma unroll
        for (int i = 0; i < 33; i++) s[i] = 0.f;
        for (int c = 0; c < NCH; c++) {
            const float* pp = ws_jp + (size_t)(c * NJ + j) * 33;
#pragma unroll
            for (int i = 0; i < 33; i++) s[i] += pp[i];
        }
        float bb[NBETA];
#pragma unroll
        for (int l = 0; l < NBETA; l++) bb[l] = betas[b * NBETA + l];
#pragma unroll
        for (int k = 0; k < 3; k++) {
            float acc = s[k];
#pragma unroll
            for (int l = 0; l < NBETA; l++) acc += bb[l] * s[3 + k * NBETA + l];
            Jl[j][k] = acc;
        }
        // Rodrigues, matching reference: angle = ||aa + 1e-8||, rd = aa/angle
        float ax = pose[b * NJ * 3 + j * 3 + 0];
        float ay = pose[b * NJ * 3 + j * 3 + 1];
        float az = pose[b * NJ * 3 + j * 3 + 2];
        float e0 = ax + 1e-8f, e1 = ay + 1e-8f, e2 = az + 1e-8f;
        float ang = sqrtf(e0 * e0 + e1 * e1 + e2 * e2);
        float inv = 1.f / ang;
        float rx = ax * inv, ry = ay * inv, rz = az * inv;
        float sn = sinf(ang), cs = cosf(ang);
        float Km[9] = {0.f, -rz, ry, rz, 0.f, -rx, -ry, rx, 0.f};
#pragma unroll
        for (int r = 0; r < 3; r++)
#pragma unroll
            for (int c = 0; c < 3; c++) {
                float kk = Km[3 * r + 0] * Km[0 + c] + Km[3 * r + 1] * Km[3 + c] +
                           Km[3 * r + 2] * Km[6 + c];
                R[3 * r + c] = ((r == c) ? 1.f : 0.f) + sn * Km[3 * r + c] + (1.f - cs) * kk;
            }
        if (j >= 1) {
#pragma unroll
            for (int e = 0; e < 9; e++) {
                int r = e / 3, c = e % 3;
                ws_pf[b * NP + (j - 1) * 9 + e] = R[e] - ((r == c) ? 1.f : 0.f);
            }
        }
    }
    __syncthreads();
    if (t < NJ) {
        int j = t;
        int p = c_par[j];
        int ps = (p < 0) ? 0 : p;
#pragma unroll
        for (int r = 0; r < 3; r++) {
            tm[j][r * 4 + 0] = R[3 * r + 0];
            tm[j][r * 4 + 1] = R[3 * r + 1];
            tm[j][r * 4 + 2] = R[3 * r + 2];
            tm[j][r * 4 + 3] = (j == 0) ? Jl[j][r] : (Jl[j][r] - Jl[ps][r]);
        }
        tm[j][12] = 0.f; tm[j][13] = 0.f; tm[j][14] = 0.f; tm[j][15] = 1.f;
    }
    __syncthreads();
    if (t < 16) ch[0][t] = tm[0][t];
    __syncthreads();
    for (int i = 1; i < NJ; i++) {
        if (t < 16) {
            int r = t >> 2, c = t & 3;
            int p = c_par[i];
            ch[i][t] = ch[p][4 * r + 0] * tm[i][0 + c] + ch[p][4 * r + 1] * tm[i][4 + c] +
                       ch[p][4 * r + 2] * tm[i][8 + c] + ch[p][4 * r + 3] * tm[i][12 + c];
        }
        __syncthreads();
    }
    if (t < NJ) {
        int j = t;
        float ib[4];
#pragma unroll
        for (int p = 0; p < 4; p++)
            ib[p] = ch[j][4 * p + 0] * Jl[j][0] + ch[j][4 * p + 1] * Jl[j][1] +
                    ch[j][4 * p + 2] * Jl[j][2];
#pragma unroll
        for (int e = 0; e < 16; e++) {
            int r = e >> 2, c = e & 3;
            float tr = ch[j][e];
            float Ae = tr - ((c == 3) ? ib[r] : 0.f);
            out[OFF_TF + (size_t)(b * NJ + j) * 16 + e] = tr;
            out[OFF_A + (size_t)(b * NJ + j) * 16 + e] = Ae;
            ws_A[(size_t)(b * NJ + j) * 16 + e] = Ae;
        }
#pragma unroll
        for (int k = 0; k < 3; k++)
            out[OFF_PJ + (size_t)(b * NJ + j) * 3 + k] = ch[j][4 * k + 3];
    }
}

// ----------- K3 (FUSED): v_posed = vt + sd@betas + pf@posedirs ; verts = (lw@A)·vp
// ROOT-CAUSE FIX (r0-r5 post-mortem): every s_load-based variant pinned VALUBusy
// at ~40% because per-bi uniform rows (pf, A) were fetched as s_load chains —
// ~200cy SMEM latency exposed per batch, unschedulable past ~2 rows. Broadcast
// operands now live in LDS (broadcast reads cost issue slots only: b64 for pf
// halves issue vs FMA, b128 for A) with occupancy raised to 4 blocks/CU so the
// LDS and VALU pipes overlap across waves. No sched_barrier (r3: pin => AGPR
// copies). Epilogue fully unrolled: acc static-indexed, vp never re-read.
// XCD swizzle keeps each XCD's pd slice L2-resident (r2-verified).
__global__ __launch_bounds__(256, 4) void k_fused(
        const float* __restrict__ vt,
        const float* __restrict__ sd,
        const float* __restrict__ betas,
        const float* __restrict__ pd,
        const float* __restrict__ ws_pf,
        const float* __restrict__ ws_A,
        const float* __restrict__ lw,
        float* __restrict__ out) {
    int id = blockIdx.x;
    int xcd = id & 7, li = id >> 3;
    int nx = (xcd < 3) ? 4 : 3;                  // 27 x-slices = 3*4 + 5*3
    if (li >= nx * (BB / TBAT)) return;          // whole-block exit (before barriers)
    int x = xcd + 8 * (li % nx);
    int b0 = (li / nx) * TBAT;
    int t = threadIdx.x;
    int v = x * 256 + t;
    bool act = (v < VV);
    int vc = act ? v : (VV - 1);                 // clamp reads; predicate writes
    int n0 = vc * 3;

    __shared__ __align__(16) float pfs[TBAT][208];   // pose_feature rows (+1 zero pad)
    __shared__ __align__(16) float As[TBAT][288];    // A[:3][:4] rows, flat 24*12
    __shared__ __align__(16) float bbs[TBAT][NBETA];

    // ---- stage broadcast operands (coalesced, all threads participate)
    for (int idx = t; idx < TBAT * NP; idx += 256) {
        int bi = idx / NP, p = idx - bi * NP;
        pfs[bi][p] = ws_pf[(size_t)(b0 + bi) * NP + p];
    }
    if (t < TBAT) pfs[t][NP] = 0.f;              // pad: clamped tail FMA adds 0
    for (int idx = t; idx < TBAT * 288; idx += 256) {
        int bi = idx / 288, r = idx - bi * 288;
        int j = r / 12, e = r - j * 12;
        As[bi][r] = ws_A[(size_t)(b0 + bi) * (NJ * 16) + j * 16 + e];
    }
    if (t < TBAT * NBETA) {
        int bi = t / NBETA, l = t - bi * NBETA;
        bbs[bi][l] = betas[(size_t)(b0 + bi) * NBETA + l];
    }
    __syncthreads();

    float acc0[TBAT], acc1[TBAT], acc2[TBAT];
#pragma unroll
    for (int bi = 0; bi < TBAT; bi++) { acc0[bi] = 0.f; acc1[bi] = 0.f; acc2[bi] = 0.f; }

    const float* __restrict__ pdp = pd + n0;

    // ---- main loop: 26 chunks of 8 rows (last chunk: row 207 clamped, pf=0)
#pragma unroll 1
    for (int c0 = 0; c0 < 208; c0 += 8) {
        float p0[8], p1[8], p2[8];
#pragma unroll
        for (int pc = 0; pc < 8; pc++) {
            int row = c0 + pc;
            row = (row < NP) ? row : (NP - 1);
            const float* rp = pdp + (size_t)row * N3;
            p0[pc] = rp[0]; p1[pc] = rp[1]; p2[pc] = rp[2];   // dwordx3/wave
        }
#pragma unroll
        for (int bi = 0; bi < TBAT; bi++) {
#pragma unroll
            for (int pc = 0; pc < 8; pc += 2) {
                float2 w2 = *(const float2*)&pfs[bi][c0 + pc];  // b64 broadcast
                acc0[bi] += w2.x * p0[pc];
                acc1[bi] += w2.x * p1[pc];
                acc2[bi] += w2.x * p2[pc];
                acc0[bi] += w2.y * p0[pc + 1];
                acc1[bi] += w2.y * p1[pc + 1];
                acc2[bi] += w2.y * p2[pc + 1];
            }
        }
    }

    // ---- per-vertex constants
    float vt0 = vt[n0], vt1 = vt[n0 + 1], vt2 = vt[n0 + 2];
    float sdv[3][NBETA];
#pragma unroll
    for (int k = 0; k < 3; k++)
#pragma unroll
        for (int l = 0; l < NBETA; l++)
            sdv[k][l] = sd[(size_t)vc * 30 + k * NBETA + l];
    float wv[NJ];
#pragma unroll
    for (int j0 = 0; j0 < NJ; j0 += 4) {
        const float4 w4 = *(const float4*)&lw[(size_t)vc * NJ + j0];  // 96B/vtx: aligned
        wv[j0 + 0] = w4.x; wv[j0 + 1] = w4.y; wv[j0 + 2] = w4.z; wv[j0 + 3] = w4.w;
    }

    // ---- epilogue, fully unrolled over bi (acc static-indexed; vp kept in regs)
#pragma unroll
    for (int bi = 0; bi < TBAT; bi++) {
        int b = b0 + bi;
        float s0 = vt0 + acc0[bi], s1 = vt1 + acc1[bi], s2 = vt2 + acc2[bi];
#pragma unroll
        for (int l = 0; l < NBETA; l++) {
            float bl = bbs[bi][l];                   // b32 broadcast
            s0 += bl * sdv[0][l];
            s1 += bl * sdv[1][l];
            s2 += bl * sdv[2][l];
        }
        if (act) {
            float* op = &out[OFF_VP + (size_t)b * N3 + n0];
            op[0] = s0; op[1] = s1; op[2] = s2;
        }
        float T[12];
#pragma unroll
        for (int e = 0; e < 12; e++) T[e] = 0.f;
#pragma unroll
        for (int j = 0; j < NJ; j++) {
            float wj = wv[j];
            const float4 a0 = *(const float4*)&As[bi][j * 12 + 0];   // b128 broadcast
            const float4 a1 = *(const float4*)&As[bi][j * 12 + 4];
            const float4 a2 = *(const float4*)&As[bi][j * 12 + 8];
            T[0] += wj * a0.x; T[1] += wj * a0.y; T[2]  += wj * a0.z; T[3]  += wj * a0.w;
            T[4] += wj * a1.x; T[5] += wj * a1.y; T[6]  += wj * a1.z; T[7]  += wj * a1.w;
            T[8] += wj * a2.x; T[9] += wj * a2.y; T[10] += wj * a2.z; T[11] += wj * a2.w;
        }
        if (act) {
            float* op = &out[OFF_VERTS + (size_t)b * N3 + n0];
            op[0] = T[0] * s0 + T[1] * s1 + T[2]  * s2 + T[3];
            op[1] = T[4] * s0 + T[5] * s1 + T[6]  * s2 + T[7];
            op[2] = T[8] * s0 + T[9] * s1 + T[10] * s2 + T[11];
        }
    }
}

extern "C" void kernel_launch(void* const* d_in, const int* in_sizes, int n_in,
                              void* d_out, int out_size, void* d_ws, size_t ws_size,
                              hipStream_t stream) {
    const float* betas = (const float*)d_in[0];
    const float* pose  = (const float*)d_in[1];
    const float* vt    = (const float*)d_in[2];
    const float* sd    = (const float*)d_in[3];
    const float* pd    = (const float*)d_in[4];
    const float* jr    = (const float*)d_in[5];
    const float* lw    = (const float*)d_in[6];
    float* out = (float*)d_out;
    float* ws = (float*)d_ws;

    k_jreg<<<dim3(NJ, NCH), 256, 0, stream>>>(jr, vt, sd, ws + WS_JP);
    k_chain<<<BB, 64, 0, stream>>>(betas, pose, ws + WS_JP, ws + WS_PF,
                                   ws + WS_A, out);
    // 8 XCDs x max 4 x-slices x 64 batch-groups = 2048 launched, 1728 live
    k_fused<<<8 * 4 * (BB / TBAT), 256, 0, stream>>>(
        vt, sd, betas, pd, ws + WS_PF, ws + WS_A, lw, out);
}

// Round 7
// 285.644 us; speedup vs baseline: 3.6116x; 3.6116x over previous
//
#include <hip/hip_runtime.h>
#include <hip/hip_bf16.h>

#define BB 512
#define VV 6890
#define NJ 24
#define NBETA 10
#define NP 207          // (24-1)*9
#define N3 (VV*3)       // 20670
#define TBAT 8          // batch tile in k_fused
#define NCH 16          // v-chunks in k_jreg
#define CHV ((VV + NCH - 1) / NCH)   // 431

// d_out element offsets (fp32), concatenated in return order:
// verts (B,V,3), posed_joints (B,J,3), A (B,J,4,4), transforms (B,J,4,4), v_posed (B,V,3)
#define OFF_VERTS 0
#define OFF_PJ   (BB*VV*3)
#define OFF_A    (OFF_PJ + BB*NJ*3)
#define OFF_TF   (OFF_A + BB*NJ*16)
#define OFF_VP   (OFF_TF + BB*NJ*16)

// ws layout (fp32 elements)
#define WS_JP   0                        // NCH*24*33 partials of [JT[3]|JS[30]]
#define WS_PF   (WS_JP + NCH*NJ*33)      // B*207 pose_feature
#define WS_A    (WS_PF + BB*NP)          // B*24*16 fp32 A

// SMPL parents are a compile-time constant in the reference — hardcoded.
__constant__ int c_par[NJ] = {-1, 0, 0, 0, 1, 2, 3, 4, 5, 6, 7, 8,
                              9, 9, 9, 12, 13, 14, 16, 17, 18, 19, 20, 21};

// ------------------------------------------------- K1: partial JT/JS sums
__global__ __launch_bounds__(256) void k_jreg(const float* __restrict__ jr,
                                              const float* __restrict__ vt,
                                              const float* __restrict__ sd,
                                              float* __restrict__ ws_jp) {
    int j = blockIdx.x, ch = blockIdx.y;
    int t = threadIdx.x;
    int v0 = ch * CHV;
    int vend = (v0 + CHV < VV) ? (v0 + CHV) : VV;

    float acc[33];
#pragma unroll
    for (int i = 0; i < 33; i++) acc[i] = 0.f;

    for (int v = v0 + t; v < vend; v += 256) {
        float a = jr[(size_t)j * VV + v];
        acc[0] += a * vt[v * 3 + 0];
        acc[1] += a * vt[v * 3 + 1];
        acc[2] += a * vt[v * 3 + 2];
        const float2* sp = (const float2*)&sd[(size_t)v * 30];   // 8B-aligned
#pragma unroll
        for (int i = 0; i < 15; i++) {
            float2 s = sp[i];
            acc[3 + 2 * i] += a * s.x;
            acc[4 + 2 * i] += a * s.y;
        }
    }

    __shared__ float red[33][256];
#pragma unroll
    for (int i = 0; i < 33; i++) red[i][t] = acc[i];
    __syncthreads();
    for (int s = 128; s > 0; s >>= 1) {
        if (t < s) {
#pragma unroll
            for (int i = 0; i < 33; i++) red[i][t] += red[i][t + s];
        }
        __syncthreads();
    }
    if (t < 33) ws_jp[(size_t)(ch * NJ + j) * 33 + t] = red[t][0];
}

// ------------------------------- K2: Jloc, Rodrigues, chain, A/transforms/joints
__global__ __launch_bounds__(64) void k_chain(
        const float* __restrict__ betas,
        const float* __restrict__ pose,
        const float* __restrict__ ws_jp,
        float* __restrict__ ws_pf,
        float* __restrict__ ws_A,
        float* __restrict__ out) {
    int b = blockIdx.x;
    int t = threadIdx.x;
    __shared__ float Jl[NJ][3];
    __shared__ float tm[NJ][16];
    __shared__ float ch[NJ][16];
    float R[9];

    if (t < NJ) {
        int j = t;
        float s[33];
#pragma unroll
        for (int i = 0; i < 33; i++) s[i] = 0.f;
        for (int c = 0; c < NCH; c++) {
            const float* pp = ws_jp + (size_t)(c * NJ + j) * 33;
#pragma unroll
            for (int i = 0; i < 33; i++) s[i] += pp[i];
        }
        float bb[NBETA];
#pragma unroll
        for (int l = 0; l < NBETA; l++) bb[l] = betas[b * NBETA + l];
#pragma unroll
        for (int k = 0; k < 3; k++) {
            float acc = s[k];
#pragma unroll
            for (int l = 0; l < NBETA; l++) acc += bb[l] * s[3 + k * NBETA + l];
            Jl[j][k] = acc;
        }
        // Rodrigues, matching reference: angle = ||aa + 1e-8||, rd = aa/angle
        float ax = pose[b * NJ * 3 + j * 3 + 0];
        float ay = pose[b * NJ * 3 + j * 3 + 1];
        float az = pose[b * NJ * 3 + j * 3 + 2];
        float e0 = ax + 1e-8f, e1 = ay + 1e-8f, e2 = az + 1e-8f;
        float ang = sqrtf(e0 * e0 + e1 * e1 + e2 * e2);
        float inv = 1.f / ang;
        float rx = ax * inv, ry = ay * inv, rz = az * inv;
        float sn = sinf(ang), cs = cosf(ang);
        float Km[9] = {0.f, -rz, ry, rz, 0.f, -rx, -ry, rx, 0.f};
#pragma unroll
        for (int r = 0; r < 3; r++)
#pragma unroll
            for (int c = 0; c < 3; c++) {
                float kk = Km[3 * r + 0] * Km[0 + c] + Km[3 * r + 1] * Km[3 + c] +
                           Km[3 * r + 2] * Km[6 + c];
                R[3 * r + c] = ((r == c) ? 1.f : 0.f) + sn * Km[3 * r + c] + (1.f - cs) * kk;
            }
        if (j >= 1) {
#pragma unroll
            for (int e = 0; e < 9; e++) {
                int r = e / 3, c = e % 3;
                ws_pf[b * NP + (j - 1) * 9 + e] = R[e] - ((r == c) ? 1.f : 0.f);
            }
        }
    }
    __syncthreads();
    if (t < NJ) {
        int j = t;
        int p = c_par[j];
        int ps = (p < 0) ? 0 : p;
#pragma unroll
        for (int r = 0; r < 3; r++) {
            tm[j][r * 4 + 0] = R[3 * r + 0];
            tm[j][r * 4 + 1] = R[3 * r + 1];
            tm[j][r * 4 + 2] = R[3 * r + 2];
            tm[j][r * 4 + 3] = (j == 0) ? Jl[j][r] : (Jl[j][r] - Jl[ps][r]);
        }
        tm[j][12] = 0.f; tm[j][13] = 0.f; tm[j][14] = 0.f; tm[j][15] = 1.f;
    }
    __syncthreads();
    if (t < 16) ch[0][t] = tm[0][t];
    __syncthreads();
    for (int i = 1; i < NJ; i++) {
        if (t < 16) {
            int r = t >> 2, c = t & 3;
            int p = c_par[i];
            ch[i][t] = ch[p][4 * r + 0] * tm[i][0 + c] + ch[p][4 * r + 1] * tm[i][4 + c] +
                       ch[p][4 * r + 2] * tm[i][8 + c] + ch[p][4 * r + 3] * tm[i][12 + c];
        }
        __syncthreads();
    }
    if (t < NJ) {
        int j = t;
        float ib[4];
#pragma unroll
        for (int p = 0; p < 4; p++)
            ib[p] = ch[j][4 * p + 0] * Jl[j][0] + ch[j][4 * p + 1] * Jl[j][1] +
                    ch[j][4 * p + 2] * Jl[j][2];
#pragma unroll
        for (int e = 0; e < 16; e++) {
            int r = e >> 2, c = e & 3;
            float tr = ch[j][e];
            float Ae = tr - ((c == 3) ? ib[r] : 0.f);
            out[OFF_TF + (size_t)(b * NJ + j) * 16 + e] = tr;
            out[OFF_A + (size_t)(b * NJ + j) * 16 + e] = Ae;
            ws_A[(size_t)(b * NJ + j) * 16 + e] = Ae;
        }
#pragma unroll
        for (int k = 0; k < 3; k++)
            out[OFF_PJ + (size_t)(b * NJ + j) * 3 + k] = ch[j][4 * k + 3];
    }
}

// ----------- K3 (FUSED): v_posed = vt + sd@betas + pf@posedirs ; verts = (lw@A)·vp
// r6 post-mortem: __launch_bounds__(256,4) made hipcc cap VGPR (64) to honor the
// occupancy minimum -> acc[] spilled to scratch in the hot loop (WRITE 1.7GB vs
// 84MB real output, dur 1ms). Fix: NO occupancy minimum (plain 256) + epilogue
// split into two passes with acc registers REUSED to carry vp (peak live ~75).
// Broadcast operands (pf, A, betas) stay in LDS — r0-r5 showed s_load chains pin
// VALUBusy at 40%; LDS broadcast reads (b64/b128) issue alongside FMA.
// XCD swizzle keeps each XCD's <=2.5MB pd slice L2-resident (r2-verified).
__global__ __launch_bounds__(256) void k_fused(
        const float* __restrict__ vt,
        const float* __restrict__ sd,
        const float* __restrict__ betas,
        const float* __restrict__ pd,
        const float* __restrict__ ws_pf,
        const float* __restrict__ ws_A,
        const float* __restrict__ lw,
        float* __restrict__ out) {
    int id = blockIdx.x;
    int xcd = id & 7, li = id >> 3;
    int nx = (xcd < 3) ? 4 : 3;                  // 27 x-slices = 3*4 + 5*3
    if (li >= nx * (BB / TBAT)) return;          // whole-block exit (before barriers)
    int x = xcd + 8 * (li % nx);
    int b0 = (li / nx) * TBAT;
    int t = threadIdx.x;
    int v = x * 256 + t;
    bool act = (v < VV);
    int vc = act ? v : (VV - 1);                 // clamp reads; predicate writes
    int n0 = vc * 3;

    __shared__ __align__(16) float pfs[TBAT][208];   // pose_feature rows (+1 zero pad)
    __shared__ __align__(16) float As[TBAT][288];    // A[:3][:4] rows, flat 24*12
    __shared__ __align__(16) float bbs[TBAT][NBETA];

    // ---- stage broadcast operands (coalesced, all threads participate)
    for (int idx = t; idx < TBAT * NP; idx += 256) {
        int bi = idx / NP, p = idx - bi * NP;
        pfs[bi][p] = ws_pf[(size_t)(b0 + bi) * NP + p];
    }
    if (t < TBAT) pfs[t][NP] = 0.f;              // pad: clamped tail FMA adds 0
    for (int idx = t; idx < TBAT * 288; idx += 256) {
        int bi = idx / 288, r = idx - bi * 288;
        int j = r / 12, e = r - j * 12;
        As[bi][r] = ws_A[(size_t)(b0 + bi) * (NJ * 16) + j * 16 + e];
    }
    if (t < TBAT * NBETA) {
        int bi = t / NBETA, l = t - bi * NBETA;
        bbs[bi][l] = betas[(size_t)(b0 + bi) * NBETA + l];
    }
    __syncthreads();

    float acc0[TBAT], acc1[TBAT], acc2[TBAT];
#pragma unroll
    for (int bi = 0; bi < TBAT; bi++) { acc0[bi] = 0.f; acc1[bi] = 0.f; acc2[bi] = 0.f; }

    const float* __restrict__ pdp = pd + n0;

    // ---- main loop: 26 chunks of 8 rows (last chunk: row 207 clamped, pf=0)
#pragma unroll 1
    for (int c0 = 0; c0 < 208; c0 += 8) {
        float p0[8], p1[8], p2[8];
#pragma unroll
        for (int pc = 0; pc < 8; pc++) {
            int row = c0 + pc;
            row = (row < NP) ? row : (NP - 1);
            const float* rp = pdp + (size_t)row * N3;
            p0[pc] = rp[0]; p1[pc] = rp[1]; p2[pc] = rp[2];   // dwordx3/wave
        }
#pragma unroll
        for (int bi = 0; bi < TBAT; bi++) {
#pragma unroll
            for (int pc = 0; pc < 8; pc += 2) {
                float2 w2 = *(const float2*)&pfs[bi][c0 + pc];  // b64 broadcast
                acc0[bi] += w2.x * p0[pc];
                acc1[bi] += w2.x * p1[pc];
                acc2[bi] += w2.x * p2[pc];
                acc0[bi] += w2.y * p0[pc + 1];
                acc1[bi] += w2.y * p1[pc + 1];
                acc2[bi] += w2.y * p2[pc + 1];
            }
        }
    }

    // ---- pass A: vp = vt + sd@betas + acc ; store vp; acc registers now carry vp
    {
        float vt0 = vt[n0], vt1 = vt[n0 + 1], vt2 = vt[n0 + 2];
        float sdv[3][NBETA];
#pragma unroll
        for (int k = 0; k < 3; k++)
#pragma unroll
            for (int l = 0; l < NBETA; l++)
                sdv[k][l] = sd[(size_t)vc * 30 + k * NBETA + l];
#pragma unroll
        for (int bi = 0; bi < TBAT; bi++) {
            float s0 = vt0 + acc0[bi], s1 = vt1 + acc1[bi], s2 = vt2 + acc2[bi];
#pragma unroll
            for (int l = 0; l < NBETA; l++) {
                float bl = bbs[bi][l];                   // b32 broadcast
                s0 += bl * sdv[0][l];
                s1 += bl * sdv[1][l];
                s2 += bl * sdv[2][l];
            }
            if (act) {
                float* op = &out[OFF_VP + (size_t)(b0 + bi) * N3 + n0];
                op[0] = s0; op[1] = s1; op[2] = s2;
            }
            acc0[bi] = s0; acc1[bi] = s1; acc2[bi] = s2;   // reuse regs (sdv dies here)
        }
    }
    __builtin_amdgcn_sched_barrier(0);           // keep pass A's live set from merging with B

    // ---- pass B: T = lw@A (LDS b128 broadcast); verts from in-register vp
    float wv[NJ];
#pragma unroll
    for (int j0 = 0; j0 < NJ; j0 += 4) {
        const float4 w4 = *(const float4*)&lw[(size_t)vc * NJ + j0];  // 96B/vtx: aligned
        wv[j0 + 0] = w4.x; wv[j0 + 1] = w4.y; wv[j0 + 2] = w4.z; wv[j0 + 3] = w4.w;
    }
#pragma unroll
    for (int bi = 0; bi < TBAT; bi++) {
        float T[12];
#pragma unroll
        for (int e = 0; e < 12; e++) T[e] = 0.f;
#pragma unroll
        for (int j = 0; j < NJ; j++) {
            float wj = wv[j];
            const float4 a0 = *(const float4*)&As[bi][j * 12 + 0];   // b128 broadcast
            const float4 a1 = *(const float4*)&As[bi][j * 12 + 4];
            const float4 a2 = *(const float4*)&As[bi][j * 12 + 8];
            T[0] += wj * a0.x; T[1] += wj * a0.y; T[2]  += wj * a0.z; T[3]  += wj * a0.w;
            T[4] += wj * a1.x; T[5] += wj * a1.y; T[6]  += wj * a1.z; T[7]  += wj * a1.w;
            T[8] += wj * a2.x; T[9] += wj * a2.y; T[10] += wj * a2.z; T[11] += wj * a2.w;
        }
        if (act) {
            float s0 = acc0[bi], s1 = acc1[bi], s2 = acc2[bi];
            float* op = &out[OFF_VERTS + (size_t)(b0 + bi) * N3 + n0];
            op[0] = T[0] * s0 + T[1] * s1 + T[2]  * s2 + T[3];
            op[1] = T[4] * s0 + T[5] * s1 + T[6]  * s2 + T[7];
            op[2] = T[8] * s0 + T[9] * s1 + T[10] * s2 + T[11];
        }
    }
}

extern "C" void kernel_launch(void* const* d_in, const int* in_sizes, int n_in,
                              void* d_out, int out_size, void* d_ws, size_t ws_size,
                              hipStream_t stream) {
    const float* betas = (const float*)d_in[0];
    const float* pose  = (const float*)d_in[1];
    const float* vt    = (const float*)d_in[2];
    const float* sd    = (const float*)d_in[3];
    const float* pd    = (const float*)d_in[4];
    const float* jr    = (const float*)d_in[5];
    const float* lw    = (const float*)d_in[6];
    float* out = (float*)d_out;
    float* ws = (float*)d_ws;

    k_jreg<<<dim3(NJ, NCH), 256, 0, stream>>>(jr, vt, sd, ws + WS_JP);
    k_chain<<<BB, 64, 0, stream>>>(betas, pose, ws + WS_JP, ws + WS_PF,
                                   ws + WS_A, out);
    // 8 XCDs x max 4 x-slices x 64 batch-groups = 2048 launched, 1728 live
    k_fused<<<8 * 4 * (BB / TBAT), 256, 0, stream>>>(
        vt, sd, betas, pd, ws + WS_PF, ws + WS_A, lw, out);
}